// Round 2
// baseline (492.246 us; speedup 1.0000x reference)
//
#include <hip/hip_runtime.h>
#include <math.h>

#define N_NODES 50000
#define N_EDGES 1600000
#define F 256
#define ALPHA 0.2f
#define NP 50048   // padded node count (multiple of 128)
#define NB 196     // coarse buckets: bucket = row >> 8 (256 rows each)
#define CAP 10240  // fixed bucket capacity (Poisson mean 8192, sigma 91 -> 22σ)
#define EPB 4096   // edges per binning block
#define NAB ((N_EDGES + EPB - 1) / EPB)  // 391
#define GEMM_BLOCKS 782  // (NP/128) * (F/128)
#define FVEC_SLOTS 2048  // grid-stride fat blocks for the projection part
#define PULL_BLOCKS 2048 // persistent pull blocks (8 per CU)
#define NW_TOT (PULL_BLOCKS * 4)  // 8192 persistent waves
#define NPW 7    // nodes per wave (ceil(50000/8192))
#define NBIN 8   // col bins (col >> 13), 4 MB Wh slice per bin

typedef short bf16x8 __attribute__((ext_vector_type(8)));
typedef float f32x4 __attribute__((ext_vector_type(4)));
typedef _Float16 half4 __attribute__((ext_vector_type(4)));
typedef _Float16 half8 __attribute__((ext_vector_type(8)));

__device__ __forceinline__ unsigned short f2bf(float f) {
  union { float f; unsigned u; } v; v.f = f;
  unsigned u = v.u;
  return (unsigned short)((u + 0x7fffu + ((u >> 16) & 1u)) >> 16);
}

__device__ __forceinline__ unsigned short f2h_bits(float f) {
  union { _Float16 h; unsigned short u; } v;
  v.h = (_Float16)f;
  return v.u;
}

__device__ __forceinline__ float h_bits2f(unsigned short u) {
  union { _Float16 h; unsigned short u; } v;
  v.u = u;
  return (float)v.h;
}

// ---- L1: prep_w: W -> Wt bf16 transposed; wa = W @ a_halves; cb; zero gcur
__global__ __launch_bounds__(256) void prep_w(const float* __restrict__ W,
                                              const float* __restrict__ a_w,
                                              const float* __restrict__ W_b,
                                              const float* __restrict__ a_b,
                                              unsigned short* __restrict__ Wt,
                                              float* __restrict__ wa,
                                              float* __restrict__ cb,
                                              int* __restrict__ gcur) {
  if (blockIdx.x == 64) {  // zero the bucket cursors (replaces memset launch)
    if (threadIdx.x < NB) gcur[threadIdx.x] = 0;
    return;
  }
  const int lane = threadIdx.x & 63, w = threadIdx.x >> 6;
  const int k = blockIdx.x * 4 + w;  // 0..255
  float4 wv = *(const float4*)(W + (size_t)k * F + lane * 4);
  float4 a1 = *(const float4*)(a_w + lane * 4);
  float4 a2 = *(const float4*)(a_w + F + lane * 4);
  Wt[(size_t)(lane * 4 + 0) * F + k] = f2bf(wv.x);
  Wt[(size_t)(lane * 4 + 1) * F + k] = f2bf(wv.y);
  Wt[(size_t)(lane * 4 + 2) * F + k] = f2bf(wv.z);
  Wt[(size_t)(lane * 4 + 3) * F + k] = f2bf(wv.w);
  float s1 = wv.x * a1.x + wv.y * a1.y + wv.z * a1.z + wv.w * a1.w;
  float s2 = wv.x * a2.x + wv.y * a2.y + wv.z * a2.z + wv.w * a2.w;
#pragma unroll
  for (int off = 32; off > 0; off >>= 1) {
    s1 += __shfl_down(s1, off, 64);
    s2 += __shfl_down(s2, off, 64);
  }
  if (lane == 0) { wa[k] = s1; wa[F + k] = s2; }
  if (blockIdx.x == 0 && w == 0) {
    float4 b = *(const float4*)(W_b + lane * 4);
    float t1 = b.x * (a1.x + a2.x) + b.y * (a1.y + a2.y) +
               b.z * (a1.z + a2.z) + b.w * (a1.w + a2.w);
#pragma unroll
    for (int off = 32; off > 0; off >>= 1) t1 += __shfl_down(t1, off, 64);
    if (lane == 0) cb[0] = t1 + a_b[0];
  }
}

// ---- L2: fused GEMM [0,782) + binA2 [782,1173) + fvec [1173,1173+2048)
#define LDSK 72
__global__ __launch_bounds__(256) void gemm_fvec_binA2(
    const float* __restrict__ x,
    const unsigned short* __restrict__ Wt,
    const float* __restrict__ bias,
    const float* __restrict__ wa,
    const int* __restrict__ row,
    const int* __restrict__ col,
    _Float16* __restrict__ Wh,
    float* __restrict__ f_dst,
    float* __restrict__ f_row,
    int* __restrict__ gcur,
    unsigned* __restrict__ gstage) {
  __shared__ char smem[2 * 128 * LDSK * 2];  // 36864 B arena
  if (blockIdx.x < GEMM_BLOCKS) {
    // ---- GEMM part: Wh(fp16) = bf16(x) @ Wt^T + bias
    short* As = (short*)smem;
    short* Bs = As + 128 * LDSK;
    const int tid = threadIdx.x;
    const int lane = tid & 63;
    const int w = tid >> 6;
    const int wm = w >> 1, wn = w & 1;
    const int m0 = (blockIdx.x >> 1) * 128;
    const int n0 = (blockIdx.x & 1) * 128;
    f32x4 acc[4][4] = {{{0.f, 0.f, 0.f, 0.f}}};
    const int srow = tid >> 3;   // 0..31
    const int schunk = tid & 7;  // 0..7
    for (int k0 = 0; k0 < F; k0 += 64) {
#pragma unroll
      for (int i = 0; i < 4; ++i) {
        int r = i * 32 + srow;
        int gm = m0 + r; if (gm > N_NODES - 1) gm = N_NODES - 1;
        const float* src = x + (size_t)gm * F + k0 + schunk * 8;
        float4 lo = *(const float4*)src;
        float4 hi = *(const float4*)(src + 4);
        bf16x8 v;
        v[0] = (short)f2bf(lo.x); v[1] = (short)f2bf(lo.y);
        v[2] = (short)f2bf(lo.z); v[3] = (short)f2bf(lo.w);
        v[4] = (short)f2bf(hi.x); v[5] = (short)f2bf(hi.y);
        v[6] = (short)f2bf(hi.z); v[7] = (short)f2bf(hi.w);
        *(bf16x8*)&As[r * LDSK + schunk * 8] = v;
        *(bf16x8*)&Bs[r * LDSK + schunk * 8] =
            *(const bf16x8*)(Wt + (size_t)(n0 + r) * F + k0 + schunk * 8);
      }
      __syncthreads();
#pragma unroll
      for (int kk = 0; kk < 64; kk += 32) {
        const int rowsel = lane & 15;
        const int ksel = kk + (lane >> 4) * 8;
        bf16x8 af[4], bfr[4];
#pragma unroll
        for (int t = 0; t < 4; ++t) {
          af[t] = *(bf16x8*)&As[(wm * 64 + t * 16 + rowsel) * LDSK + ksel];
          bfr[t] = *(bf16x8*)&Bs[(wn * 64 + t * 16 + rowsel) * LDSK + ksel];
        }
#pragma unroll
        for (int mi = 0; mi < 4; ++mi)
#pragma unroll
          for (int nj = 0; nj < 4; ++nj)
            acc[mi][nj] = __builtin_amdgcn_mfma_f32_16x16x32_bf16(
                af[mi], bfr[nj], acc[mi][nj], 0, 0, 0);
      }
      __syncthreads();
    }
    const int crow = (lane >> 4) * 4;
    const int ccol = lane & 15;
#pragma unroll
    for (int nj = 0; nj < 4; ++nj) {
      int gc = n0 + wn * 64 + nj * 16 + ccol;
      float bv = bias[gc];
#pragma unroll
      for (int mi = 0; mi < 4; ++mi) {
        int gr = m0 + wm * 64 + mi * 16 + crow;
#pragma unroll
        for (int r = 0; r < 4; ++r)
          Wh[(size_t)(gr + r) * F + gc] = (_Float16)(acc[mi][nj][r] + bv);
      }
    }
    return;
  }
  if (blockIdx.x < GEMM_BLOCKS + NAB) {
    // ---- binA2 part
    int* h = (int*)smem;
    int* lofs = h + NB;
    int* lcur = lofs + NB;
    int* gb = lcur + NB;
    unsigned* stage = (unsigned*)(gb + NB);  // EPB entries
    const int t = threadIdx.x;
    for (int i = t; i < NB; i += 256) { h[i] = 0; lcur[i] = 0; }
    __syncthreads();
    const int base = (blockIdx.x - GEMM_BLOCKS) * EPB;
    const int cnt = min(EPB, N_EDGES - base);
#pragma unroll
    for (int j = 0; j < 16; ++j) {
      int k = base + j * 256 + t;
      if (k < N_EDGES) atomicAdd(&h[row[k] >> 8], 1);
    }
    __syncthreads();
    if (t == 0) {
      int run = 0;
      for (int i = 0; i < NB; ++i) { lofs[i] = run; run += h[i]; }
    }
    __syncthreads();
    if (t < NB && h[t] > 0) gb[t] = atomicAdd(&gcur[t], h[t]);
    __syncthreads();
#pragma unroll
    for (int j = 0; j < 16; ++j) {
      int k = base + j * 256 + t;
      if (k < N_EDGES) {
        int r = row[k], b = r >> 8;
        int lp = lofs[b] + atomicAdd(&lcur[b], 1);
        stage[lp] = ((unsigned)b << 24) | ((unsigned)(r & 255) << 16) |
                    (unsigned)col[k];
      }
    }
    __syncthreads();
#pragma unroll
    for (int j = 0; j < 16; ++j) {
      int s = j * 256 + t;
      if (s < cnt) {
        unsigned wv = stage[s];
        int b = wv >> 24;
        gstage[(size_t)b * CAP + gb[b] + (s - lofs[b])] = wv & 0x00FFFFFFu;
      }
    }
    return;
  }
  // ---- fvec part: grid-stride fat blocks (4 nodes/iter/block)
  const int lane = threadIdx.x & 63, w = threadIdx.x >> 6;
  const int slot = blockIdx.x - GEMM_BLOCKS - NAB;
  float4 v1 = *(const float4*)(wa + lane * 4);
  float4 v2 = *(const float4*)(wa + F + lane * 4);
  for (int node = slot * 4 + w; node < N_NODES; node += FVEC_SLOTS * 4) {
    float4 xv = *(const float4*)(x + (size_t)node * F + lane * 4);
    float s1 = xv.x * v1.x + xv.y * v1.y + xv.z * v1.z + xv.w * v1.w;
    float s2 = xv.x * v2.x + xv.y * v2.y + xv.z * v2.z + xv.w * v2.w;
#pragma unroll
    for (int off = 32; off > 0; off >>= 1) {
      s1 += __shfl_down(s1, off, 64);
      s2 += __shfl_down(s2, off, 64);
    }
    if (lane == 0) { f_dst[node] = s1; f_row[node] = s2; }
  }
}

// ---- L3: binB (512 thr): per-(row,colbin) histogram -> entries placed
// COL-SORTED within each row (8 bins, q = col>>13). Additionally exports the
// per-(row,bin) absolute start offsets (bstart) so the pull kernel can do a
// globally phase-synchronized bin sweep.
__global__ __launch_bounds__(512) void binB(const int* __restrict__ gcur,
                                            const unsigned* __restrict__ gstage,
                                            const float* __restrict__ f_dst,
                                            const float* __restrict__ f_row,
                                            const float* __restrict__ cb,
                                            int2* __restrict__ rsc,
                                            float* __restrict__ inv_denom,
                                            unsigned* __restrict__ csr,
                                            int* __restrict__ bstart) {
  __shared__ int cnt2[2048];  // per (row, colbin)
  __shared__ int cur2[2048];
  __shared__ int rcnt[256], rbase[256];
  __shared__ float dsum[256];
  const int t = threadIdx.x;
  const int b = blockIdx.x;
  for (int i = t; i < 2048; i += 512) cnt2[i] = 0;
  if (t < 256) dsum[t] = 0.f;
  __syncthreads();
  const int nb = gcur[b];
  const int start = b * CAP;
  const float cbs = cb[0];
  for (int s = t; s < nb; s += 512) {
    unsigned wv = gstage[start + s];
    int key = (((wv >> 16) & 255) << 3) | ((wv & 0xFFFFu) >> 13);
    atomicAdd(&cnt2[key], 1);
  }
  __syncthreads();
  if (t < 256) {
    int tot = 0;
#pragma unroll
    for (int q = 0; q < 8; ++q) tot += cnt2[t * 8 + q];
    rcnt[t] = tot;
  }
  __syncthreads();
  if (t == 0) {
    int run = 0;
    for (int i = 0; i < 256; ++i) { rbase[i] = run; run += rcnt[i]; }
  }
  __syncthreads();
  if (t < 256) {
    int base = start + rbase[t];
    int g = (b << 8) + t;
    if (g < N_NODES) rsc[g] = make_int2(base, rcnt[t]);
    int run = base;
    int bs[8];
#pragma unroll
    for (int q = 0; q < 8; ++q) {
      cur2[t * 8 + q] = run;
      bs[q] = run;
      run += cnt2[t * 8 + q];
    }
    if (g < N_NODES) {
      *(int4*)&bstart[(size_t)g * 8]     = make_int4(bs[0], bs[1], bs[2], bs[3]);
      *(int4*)&bstart[(size_t)g * 8 + 4] = make_int4(bs[4], bs[5], bs[6], bs[7]);
    }
  }
  __syncthreads();
  for (int s = t; s < nb; s += 512) {
    unsigned wv = gstage[start + s];
    int lr = (wv >> 16) & 255;
    int c = wv & 0xFFFF;
    float ev = f_dst[c] + f_row[(b << 8) + lr] + cbs;
    ev = ev > 0.f ? ev : ALPHA * ev;
    float ex = __expf(ev);
    int p = atomicAdd(&cur2[(lr << 3) | (c >> 13)], 1);  // absolute index
    csr[p] = ((unsigned)f2h_bits(ex) << 16) | (unsigned)c;
    atomicAdd(&dsum[lr], ex);
  }
  __syncthreads();
  if (t < 256) {
    int g = (b << 8) + t;
    if (g < N_NODES) inv_denom[g] = (rcnt[t] > 0) ? (1.0f / dsum[t]) : 0.f;
  }
}

// ---- L4: pull, phase-synchronized col-bin sweep.
// All 8192 persistent waves process col-bin q of ALL their nodes before
// moving to bin q+1 -> at any instant the machine touches one 4 MB Wh slice
// -> each XCD's L2 sees each slice ~once (FETCH floor 8*25.6 = 205 MB).
// Pair-lane: lanes 0-31 even edges, 32-63 odd edges, 8 channels/lane (16 B
// half8 gather). Accumulators persist across phases (static-indexed, NPW=7).
__global__ __launch_bounds__(256) void gat_pull(const int2* __restrict__ rsc,
                                                const unsigned* __restrict__ csr,
                                                const float* __restrict__ inv_denom,
                                                const int* __restrict__ bstart,
                                                const _Float16* __restrict__ Wh,
                                                float* __restrict__ out) {
  const int lane = threadIdx.x & 63;
  const int eo = lane >> 5;        // 0: even edges, 1: odd edges
  const int l32 = lane & 31;
  const int wid = blockIdx.x * 4 + (threadIdx.x >> 6);
  const char* whb = (const char*)Wh;
  const unsigned chanoff = (unsigned)l32 * 16u;  // 8 fp16 channels / lane
  float acc[NPW][8];
  int p[NPW], pend[NPW];
#pragma unroll
  for (int jn = 0; jn < NPW; ++jn) {
#pragma unroll
    for (int c = 0; c < 8; ++c) acc[jn][c] = 0.f;
    int i = wid + jn * NW_TOT;
    if (i < N_NODES) {
      int2 rc = rsc[i];
      p[jn] = rc.x;            // == bstart[i*8 + 0]
      pend[jn] = rc.x + rc.y;
    } else {
      p[jn] = 0; pend[jn] = 0;
    }
  }
  for (int q = 0; q < NBIN; ++q) {
#pragma unroll
    for (int jn = 0; jn < NPW; ++jn) {
      int i = wid + jn * NW_TOT;
      if (i >= N_NODES) continue;
      int pe = (q < NBIN - 1) ? bstart[(size_t)i * 8 + q + 1] : pend[jn];
      int pp = p[jn];
      if (pp >= pe) { p[jn] = pe; continue; }
      const int s0 = pp;  // clamp target (in-bounds for this segment)
      // mid: 8 edges / iter (4 pairs), unclamped
      for (; pp + 8 <= pe; pp += 8) {
        unsigned wv[4];
#pragma unroll
        for (int j = 0; j < 4; ++j) wv[j] = csr[pp + 2 * j + eo];
        half8 v[4];
#pragma unroll
        for (int j = 0; j < 4; ++j) {
          unsigned off = (wv[j] & 0xFFFFu) * 512u + chanoff;
          v[j] = *(const half8*)(whb + off);
        }
#pragma unroll
        for (int j = 0; j < 4; ++j) {
          float xw = h_bits2f((unsigned short)(wv[j] >> 16));
#pragma unroll
          for (int c = 0; c < 8; ++c) acc[jn][c] += xw * (float)v[j][c];
        }
      }
      // tail: 4 edges / iter (2 pairs), clamped
      for (; pp < pe; pp += 4) {
        int q0 = pp + eo, q1 = pp + 2 + eo;
        unsigned w0 = csr[q0 < pe ? q0 : s0];
        unsigned w1 = csr[q1 < pe ? q1 : s0];
        unsigned off0 = (w0 & 0xFFFFu) * 512u + chanoff;
        unsigned off1 = (w1 & 0xFFFFu) * 512u + chanoff;
        half8 v0 = *(const half8*)(whb + off0);
        half8 v1 = *(const half8*)(whb + off1);
        float xw0 = (q0 < pe) ? h_bits2f((unsigned short)(w0 >> 16)) : 0.f;
        float xw1 = (q1 < pe) ? h_bits2f((unsigned short)(w1 >> 16)) : 0.f;
#pragma unroll
        for (int c = 0; c < 8; ++c) acc[jn][c] += xw0 * (float)v0[c];
#pragma unroll
        for (int c = 0; c < 8; ++c) acc[jn][c] += xw1 * (float)v1[c];
      }
      p[jn] = pe;
    }
  }
  // finalize: combine even/odd halves, scale, relu, store
#pragma unroll
  for (int jn = 0; jn < NPW; ++jn) {
    int i = wid + jn * NW_TOT;
    if (i >= N_NODES) continue;
#pragma unroll
    for (int c = 0; c < 8; ++c) acc[jn][c] += __shfl_xor(acc[jn][c], 32, 64);
    const float inv = inv_denom[i];
    float r0 = eo ? acc[jn][4] : acc[jn][0];
    float r1 = eo ? acc[jn][5] : acc[jn][1];
    float r2 = eo ? acc[jn][6] : acc[jn][2];
    float r3 = eo ? acc[jn][7] : acc[jn][3];
    float4 o = make_float4(fmaxf(r0 * inv, 0.f), fmaxf(r1 * inv, 0.f),
                           fmaxf(r2 * inv, 0.f), fmaxf(r3 * inv, 0.f));
    ((float4*)out)[(size_t)i * 64 + l32 * 2 + eo] = o;
  }
}

extern "C" void kernel_launch(void* const* d_in, const int* in_sizes, int n_in,
                              void* d_out, int out_size, void* d_ws, size_t ws_size,
                              hipStream_t stream) {
  const float* x   = (const float*)d_in[0];
  const float* W_w = (const float*)d_in[1];
  const float* W_b = (const float*)d_in[2];
  const float* a_w = (const float*)d_in[3];
  const float* a_b = (const float*)d_in[4];
  const int*   row = (const int*)d_in[5];
  const int*   col = (const int*)d_in[6];
  float* out = (float*)d_out;

  float* ws = (float*)d_ws;
  size_t off = 0;
  _Float16* Wh = (_Float16*)(ws + off); off += (size_t)NP * F / 2;       // fp16
  unsigned short* Wt = (unsigned short*)(ws + off); off += (F * F) / 2;  // bf16
  float* wa = ws + off;            off += 2 * F;
  float* cb = ws + off;            off += 8;
  float* f_dst = ws + off;         off += NP;
  float* f_row = ws + off;         off += NP;
  int* gcur = (int*)(ws + off);    off += NB;
  int2* rsc = (int2*)(ws + off);   off += 2 * (size_t)NP;
  float* inv_denom = (float*)(ws + off); off += NP;
  unsigned* gstage = (unsigned*)(ws + off); off += (size_t)NB * CAP;
  unsigned* csr = (unsigned*)(ws + off); off += (size_t)NB * CAP;
  int* bstart = (int*)(ws + off);  off += (size_t)NP * 8;
  (void)ws_size; (void)in_sizes; (void)n_in; (void)out_size;

  hipLaunchKernelGGL(prep_w, dim3(65), dim3(256), 0, stream, W_w, a_w, W_b,
                     a_b, Wt, wa, cb, gcur);
  hipLaunchKernelGGL(gemm_fvec_binA2, dim3(GEMM_BLOCKS + NAB + FVEC_SLOTS),
                     dim3(256), 0, stream, x, Wt, W_b, wa, row, col, Wh,
                     f_dst, f_row, gcur, gstage);
  hipLaunchKernelGGL(binB, dim3(NB), dim3(512), 0, stream, gcur, gstage,
                     f_dst, f_row, cb, rsc, inv_denom, csr, bstart);
  hipLaunchKernelGGL(gat_pull, dim3(PULL_BLOCKS), dim3(256), 0, stream,
                     rsc, csr, inv_denom, bstart, Wh, out);
}

// Round 3
// 332.422 us; speedup vs baseline: 1.4808x; 1.4808x over previous
//
#include <hip/hip_runtime.h>
#include <math.h>

#define N_NODES 50000
#define N_EDGES 1600000
#define F 256
#define ALPHA 0.2f
#define NP 50048   // padded node count (multiple of 128)
#define NB 196     // coarse buckets: bucket = row >> 8 (256 rows each)
#define CAP 10240  // fixed bucket capacity (Poisson mean 8192, sigma 91 -> 22σ)
#define EPB 4096   // edges per binning block
#define NAB ((N_EDGES + EPB - 1) / EPB)  // 391
#define GEMM_BLOCKS 782  // (NP/128) * (F/128)
#define FVEC_SLOTS 2048  // grid-stride fat blocks for the projection part
#define PULL_BLOCKS 2048 // persistent pull blocks (8 per CU)
#define NW_TOT (PULL_BLOCKS * 4)  // 8192 persistent waves
#define NPW 7    // nodes per wave (ceil(50000/8192))
#define NBIN 8   // col bins (col >> 13), 3.2 MB Wh slice per bin

typedef short bf16x8 __attribute__((ext_vector_type(8)));
typedef float f32x4 __attribute__((ext_vector_type(4)));
typedef _Float16 half4 __attribute__((ext_vector_type(4)));
typedef _Float16 half8 __attribute__((ext_vector_type(8)));

__device__ __forceinline__ unsigned short f2bf(float f) {
  union { float f; unsigned u; } v; v.f = f;
  unsigned u = v.u;
  return (unsigned short)((u + 0x7fffu + ((u >> 16) & 1u)) >> 16);
}

__device__ __forceinline__ unsigned short f2h_bits(float f) {
  union { _Float16 h; unsigned short u; } v;
  v.h = (_Float16)f;
  return v.u;
}

__device__ __forceinline__ float h_bits2f(unsigned short u) {
  union { _Float16 h; unsigned short u; } v;
  v.u = u;
  return (float)v.h;
}

// ---- L1: prep_w: W -> Wt bf16 transposed; wa = W @ a_halves; cb; zero gcur
__global__ __launch_bounds__(256) void prep_w(const float* __restrict__ W,
                                              const float* __restrict__ a_w,
                                              const float* __restrict__ W_b,
                                              const float* __restrict__ a_b,
                                              unsigned short* __restrict__ Wt,
                                              float* __restrict__ wa,
                                              float* __restrict__ cb,
                                              int* __restrict__ gcur) {
  if (blockIdx.x == 64) {  // zero the bucket cursors (replaces memset launch)
    if (threadIdx.x < NB) gcur[threadIdx.x] = 0;
    return;
  }
  const int lane = threadIdx.x & 63, w = threadIdx.x >> 6;
  const int k = blockIdx.x * 4 + w;  // 0..255
  float4 wv = *(const float4*)(W + (size_t)k * F + lane * 4);
  float4 a1 = *(const float4*)(a_w + lane * 4);
  float4 a2 = *(const float4*)(a_w + F + lane * 4);
  Wt[(size_t)(lane * 4 + 0) * F + k] = f2bf(wv.x);
  Wt[(size_t)(lane * 4 + 1) * F + k] = f2bf(wv.y);
  Wt[(size_t)(lane * 4 + 2) * F + k] = f2bf(wv.z);
  Wt[(size_t)(lane * 4 + 3) * F + k] = f2bf(wv.w);
  float s1 = wv.x * a1.x + wv.y * a1.y + wv.z * a1.z + wv.w * a1.w;
  float s2 = wv.x * a2.x + wv.y * a2.y + wv.z * a2.z + wv.w * a2.w;
#pragma unroll
  for (int off = 32; off > 0; off >>= 1) {
    s1 += __shfl_down(s1, off, 64);
    s2 += __shfl_down(s2, off, 64);
  }
  if (lane == 0) { wa[k] = s1; wa[F + k] = s2; }
  if (blockIdx.x == 0 && w == 0) {
    float4 b = *(const float4*)(W_b + lane * 4);
    float t1 = b.x * (a1.x + a2.x) + b.y * (a1.y + a2.y) +
               b.z * (a1.z + a2.z) + b.w * (a1.w + a2.w);
#pragma unroll
    for (int off = 32; off > 0; off >>= 1) t1 += __shfl_down(t1, off, 64);
    if (lane == 0) cb[0] = t1 + a_b[0];
  }
}

// ---- L2: fused GEMM [0,782) + binA2 [782,1173) + fvec [1173,1173+2048)
#define LDSK 72
__global__ __launch_bounds__(256) void gemm_fvec_binA2(
    const float* __restrict__ x,
    const unsigned short* __restrict__ Wt,
    const float* __restrict__ bias,
    const float* __restrict__ wa,
    const int* __restrict__ row,
    const int* __restrict__ col,
    _Float16* __restrict__ Wh,
    float* __restrict__ f_dst,
    float* __restrict__ f_row,
    int* __restrict__ gcur,
    unsigned* __restrict__ gstage) {
  __shared__ char smem[2 * 128 * LDSK * 2];  // 36864 B arena
  if (blockIdx.x < GEMM_BLOCKS) {
    // ---- GEMM part: Wh(fp16) = bf16(x) @ Wt^T + bias
    short* As = (short*)smem;
    short* Bs = As + 128 * LDSK;
    const int tid = threadIdx.x;
    const int lane = tid & 63;
    const int w = tid >> 6;
    const int wm = w >> 1, wn = w & 1;
    const int m0 = (blockIdx.x >> 1) * 128;
    const int n0 = (blockIdx.x & 1) * 128;
    f32x4 acc[4][4] = {{{0.f, 0.f, 0.f, 0.f}}};
    const int srow = tid >> 3;   // 0..31
    const int schunk = tid & 7;  // 0..7
    for (int k0 = 0; k0 < F; k0 += 64) {
#pragma unroll
      for (int i = 0; i < 4; ++i) {
        int r = i * 32 + srow;
        int gm = m0 + r; if (gm > N_NODES - 1) gm = N_NODES - 1;
        const float* src = x + (size_t)gm * F + k0 + schunk * 8;
        float4 lo = *(const float4*)src;
        float4 hi = *(const float4*)(src + 4);
        bf16x8 v;
        v[0] = (short)f2bf(lo.x); v[1] = (short)f2bf(lo.y);
        v[2] = (short)f2bf(lo.z); v[3] = (short)f2bf(lo.w);
        v[4] = (short)f2bf(hi.x); v[5] = (short)f2bf(hi.y);
        v[6] = (short)f2bf(hi.z); v[7] = (short)f2bf(hi.w);
        *(bf16x8*)&As[r * LDSK + schunk * 8] = v;
        *(bf16x8*)&Bs[r * LDSK + schunk * 8] =
            *(const bf16x8*)(Wt + (size_t)(n0 + r) * F + k0 + schunk * 8);
      }
      __syncthreads();
#pragma unroll
      for (int kk = 0; kk < 64; kk += 32) {
        const int rowsel = lane & 15;
        const int ksel = kk + (lane >> 4) * 8;
        bf16x8 af[4], bfr[4];
#pragma unroll
        for (int t = 0; t < 4; ++t) {
          af[t] = *(bf16x8*)&As[(wm * 64 + t * 16 + rowsel) * LDSK + ksel];
          bfr[t] = *(bf16x8*)&Bs[(wn * 64 + t * 16 + rowsel) * LDSK + ksel];
        }
#pragma unroll
        for (int mi = 0; mi < 4; ++mi)
#pragma unroll
          for (int nj = 0; nj < 4; ++nj)
            acc[mi][nj] = __builtin_amdgcn_mfma_f32_16x16x32_bf16(
                af[mi], bfr[nj], acc[mi][nj], 0, 0, 0);
      }
      __syncthreads();
    }
    const int crow = (lane >> 4) * 4;
    const int ccol = lane & 15;
#pragma unroll
    for (int nj = 0; nj < 4; ++nj) {
      int gc = n0 + wn * 64 + nj * 16 + ccol;
      float bv = bias[gc];
#pragma unroll
      for (int mi = 0; mi < 4; ++mi) {
        int gr = m0 + wm * 64 + mi * 16 + crow;
#pragma unroll
        for (int r = 0; r < 4; ++r)
          Wh[(size_t)(gr + r) * F + gc] = (_Float16)(acc[mi][nj][r] + bv);
      }
    }
    return;
  }
  if (blockIdx.x < GEMM_BLOCKS + NAB) {
    // ---- binA2 part
    int* h = (int*)smem;
    int* lofs = h + NB;
    int* lcur = lofs + NB;
    int* gb = lcur + NB;
    unsigned* stage = (unsigned*)(gb + NB);  // EPB entries
    const int t = threadIdx.x;
    for (int i = t; i < NB; i += 256) { h[i] = 0; lcur[i] = 0; }
    __syncthreads();
    const int base = (blockIdx.x - GEMM_BLOCKS) * EPB;
    const int cnt = min(EPB, N_EDGES - base);
#pragma unroll
    for (int j = 0; j < 16; ++j) {
      int k = base + j * 256 + t;
      if (k < N_EDGES) atomicAdd(&h[row[k] >> 8], 1);
    }
    __syncthreads();
    if (t == 0) {
      int run = 0;
      for (int i = 0; i < NB; ++i) { lofs[i] = run; run += h[i]; }
    }
    __syncthreads();
    if (t < NB && h[t] > 0) gb[t] = atomicAdd(&gcur[t], h[t]);
    __syncthreads();
#pragma unroll
    for (int j = 0; j < 16; ++j) {
      int k = base + j * 256 + t;
      if (k < N_EDGES) {
        int r = row[k], b = r >> 8;
        int lp = lofs[b] + atomicAdd(&lcur[b], 1);
        stage[lp] = ((unsigned)b << 24) | ((unsigned)(r & 255) << 16) |
                    (unsigned)col[k];
      }
    }
    __syncthreads();
#pragma unroll
    for (int j = 0; j < 16; ++j) {
      int s = j * 256 + t;
      if (s < cnt) {
        unsigned wv = stage[s];
        int b = wv >> 24;
        gstage[(size_t)b * CAP + gb[b] + (s - lofs[b])] = wv & 0x00FFFFFFu;
      }
    }
    return;
  }
  // ---- fvec part: grid-stride fat blocks (4 nodes/iter/block)
  const int lane = threadIdx.x & 63, w = threadIdx.x >> 6;
  const int slot = blockIdx.x - GEMM_BLOCKS - NAB;
  float4 v1 = *(const float4*)(wa + lane * 4);
  float4 v2 = *(const float4*)(wa + F + lane * 4);
  for (int node = slot * 4 + w; node < N_NODES; node += FVEC_SLOTS * 4) {
    float4 xv = *(const float4*)(x + (size_t)node * F + lane * 4);
    float s1 = xv.x * v1.x + xv.y * v1.y + xv.z * v1.z + xv.w * v1.w;
    float s2 = xv.x * v2.x + xv.y * v2.y + xv.z * v2.z + xv.w * v2.w;
#pragma unroll
    for (int off = 32; off > 0; off >>= 1) {
      s1 += __shfl_down(s1, off, 64);
      s2 += __shfl_down(s2, off, 64);
    }
    if (lane == 0) { f_dst[node] = s1; f_row[node] = s2; }
  }
}

// ---- L3: binB (512 thr): per-(row,colbin) histogram -> entries placed
// COL-SORTED within each row (8 bins, q = col>>13). Additionally exports the
// per-(row,bin) absolute start offsets (bstart) so the pull kernel can do a
// globally phase-synchronized bin sweep.
__global__ __launch_bounds__(512) void binB(const int* __restrict__ gcur,
                                            const unsigned* __restrict__ gstage,
                                            const float* __restrict__ f_dst,
                                            const float* __restrict__ f_row,
                                            const float* __restrict__ cb,
                                            int2* __restrict__ rsc,
                                            float* __restrict__ inv_denom,
                                            unsigned* __restrict__ csr,
                                            int* __restrict__ bstart) {
  __shared__ int cnt2[2048];  // per (row, colbin)
  __shared__ int cur2[2048];
  __shared__ int rcnt[256], rbase[256];
  __shared__ float dsum[256];
  const int t = threadIdx.x;
  const int b = blockIdx.x;
  for (int i = t; i < 2048; i += 512) cnt2[i] = 0;
  if (t < 256) dsum[t] = 0.f;
  __syncthreads();
  const int nb = gcur[b];
  const int start = b * CAP;
  const float cbs = cb[0];
  for (int s = t; s < nb; s += 512) {
    unsigned wv = gstage[start + s];
    int key = (((wv >> 16) & 255) << 3) | ((wv & 0xFFFFu) >> 13);
    atomicAdd(&cnt2[key], 1);
  }
  __syncthreads();
  if (t < 256) {
    int tot = 0;
#pragma unroll
    for (int q = 0; q < 8; ++q) tot += cnt2[t * 8 + q];
    rcnt[t] = tot;
  }
  __syncthreads();
  if (t == 0) {
    int run = 0;
    for (int i = 0; i < 256; ++i) { rbase[i] = run; run += rcnt[i]; }
  }
  __syncthreads();
  if (t < 256) {
    int base = start + rbase[t];
    int g = (b << 8) + t;
    if (g < N_NODES) rsc[g] = make_int2(base, rcnt[t]);
    int run = base;
    int bs[8];
#pragma unroll
    for (int q = 0; q < 8; ++q) {
      cur2[t * 8 + q] = run;
      bs[q] = run;
      run += cnt2[t * 8 + q];
    }
    if (g < N_NODES) {
      *(int4*)&bstart[(size_t)g * 8]     = make_int4(bs[0], bs[1], bs[2], bs[3]);
      *(int4*)&bstart[(size_t)g * 8 + 4] = make_int4(bs[4], bs[5], bs[6], bs[7]);
    }
  }
  __syncthreads();
  for (int s = t; s < nb; s += 512) {
    unsigned wv = gstage[start + s];
    int lr = (wv >> 16) & 255;
    int c = wv & 0xFFFF;
    float ev = f_dst[c] + f_row[(b << 8) + lr] + cbs;
    ev = ev > 0.f ? ev : ALPHA * ev;
    float ex = __expf(ev);
    int p = atomicAdd(&cur2[(lr << 3) | (c >> 13)], 1);  // absolute index
    csr[p] = ((unsigned)f2h_bits(ex) << 16) | (unsigned)c;
    atomicAdd(&dsum[lr], ex);
  }
  __syncthreads();
  if (t < 256) {
    int g = (b << 8) + t;
    if (g < N_NODES) inv_denom[g] = (rcnt[t] > 0) ? (1.0f / dsum[t]) : 0.f;
  }
}

// ---- L4: pull, phase-synchronized col-bin sweep, SPILL-PROOF state.
// Full-wave-per-edge: all 64 lanes read one edge's Wh row (half4 = 8 B/lane),
// lane owns channels [lane*4, lane*4+4). Persistent state per thread is just
// acc 4 f32 x NPW=7 nodes (static arrays a0..a3) + pend[7] = 35 VGPR.
// Per-phase segment bounds re-loaded from bstart (no carried pointers).
// All 8192 waves sweep col-bin q together -> instantaneous Wh working set
// ~1 slice (3.2 MB) per XCD L2 instead of the whole 25.6 MB table.
__global__ __launch_bounds__(256) void gat_pull(const int2* __restrict__ rsc,
                                                const unsigned* __restrict__ csr,
                                                const float* __restrict__ inv_denom,
                                                const int* __restrict__ bstart,
                                                const _Float16* __restrict__ Wh,
                                                float* __restrict__ out) {
  const int lane = threadIdx.x & 63;
  const int wid = blockIdx.x * 4 + (threadIdx.x >> 6);
  const char* whb = (const char*)Wh;
  const unsigned chanoff = (unsigned)lane * 8u;  // 4 fp16 channels / lane
  float a0[NPW], a1[NPW], a2[NPW], a3[NPW];
  int pend[NPW];
#pragma unroll
  for (int jn = 0; jn < NPW; ++jn) {
    a0[jn] = a1[jn] = a2[jn] = a3[jn] = 0.f;
    int i = wid + jn * NW_TOT;
    if (i < N_NODES) {
      int2 rc = rsc[i];
      pend[jn] = rc.x + rc.y;
    } else {
      pend[jn] = 0;
    }
  }
  for (int q = 0; q < NBIN; ++q) {
#pragma unroll
    for (int jn = 0; jn < NPW; ++jn) {
      int i = wid + jn * NW_TOT;
      if (i >= N_NODES) continue;
      int pp = bstart[(size_t)i * 8 + q];
      int pe = (q == NBIN - 1) ? pend[jn] : bstart[(size_t)i * 8 + q + 1];
      // 4-edge step
      for (; pp + 4 <= pe; pp += 4) {
        unsigned w0 = csr[pp], w1 = csr[pp + 1], w2 = csr[pp + 2],
                 w3 = csr[pp + 3];
        half4 v0 = *(const half4*)(whb + (w0 & 0xFFFFu) * 512u + chanoff);
        half4 v1 = *(const half4*)(whb + (w1 & 0xFFFFu) * 512u + chanoff);
        half4 v2 = *(const half4*)(whb + (w2 & 0xFFFFu) * 512u + chanoff);
        half4 v3 = *(const half4*)(whb + (w3 & 0xFFFFu) * 512u + chanoff);
        float x0 = h_bits2f((unsigned short)(w0 >> 16));
        float x1 = h_bits2f((unsigned short)(w1 >> 16));
        float x2 = h_bits2f((unsigned short)(w2 >> 16));
        float x3 = h_bits2f((unsigned short)(w3 >> 16));
        a0[jn] += x0 * (float)v0[0]; a1[jn] += x0 * (float)v0[1];
        a2[jn] += x0 * (float)v0[2]; a3[jn] += x0 * (float)v0[3];
        a0[jn] += x1 * (float)v1[0]; a1[jn] += x1 * (float)v1[1];
        a2[jn] += x1 * (float)v1[2]; a3[jn] += x1 * (float)v1[3];
        a0[jn] += x2 * (float)v2[0]; a1[jn] += x2 * (float)v2[1];
        a2[jn] += x2 * (float)v2[2]; a3[jn] += x2 * (float)v2[3];
        a0[jn] += x3 * (float)v3[0]; a1[jn] += x3 * (float)v3[1];
        a2[jn] += x3 * (float)v3[2]; a3[jn] += x3 * (float)v3[3];
      }
      // 2-edge step
      if (pp + 2 <= pe) {
        unsigned w0 = csr[pp], w1 = csr[pp + 1];
        half4 v0 = *(const half4*)(whb + (w0 & 0xFFFFu) * 512u + chanoff);
        half4 v1 = *(const half4*)(whb + (w1 & 0xFFFFu) * 512u + chanoff);
        float x0 = h_bits2f((unsigned short)(w0 >> 16));
        float x1 = h_bits2f((unsigned short)(w1 >> 16));
        a0[jn] += x0 * (float)v0[0]; a1[jn] += x0 * (float)v0[1];
        a2[jn] += x0 * (float)v0[2]; a3[jn] += x0 * (float)v0[3];
        a0[jn] += x1 * (float)v1[0]; a1[jn] += x1 * (float)v1[1];
        a2[jn] += x1 * (float)v1[2]; a3[jn] += x1 * (float)v1[3];
        pp += 2;
      }
      // 1-edge tail
      if (pp < pe) {
        unsigned w0 = csr[pp];
        half4 v0 = *(const half4*)(whb + (w0 & 0xFFFFu) * 512u + chanoff);
        float x0 = h_bits2f((unsigned short)(w0 >> 16));
        a0[jn] += x0 * (float)v0[0]; a1[jn] += x0 * (float)v0[1];
        a2[jn] += x0 * (float)v0[2]; a3[jn] += x0 * (float)v0[3];
      }
    }
  }
  // finalize: scale, relu, store (lane owns its 4 channels directly)
#pragma unroll
  for (int jn = 0; jn < NPW; ++jn) {
    int i = wid + jn * NW_TOT;
    if (i >= N_NODES) continue;
    const float inv = inv_denom[i];
    float4 o = make_float4(fmaxf(a0[jn] * inv, 0.f), fmaxf(a1[jn] * inv, 0.f),
                           fmaxf(a2[jn] * inv, 0.f), fmaxf(a3[jn] * inv, 0.f));
    ((float4*)out)[(size_t)i * 64 + lane] = o;
  }
}

extern "C" void kernel_launch(void* const* d_in, const int* in_sizes, int n_in,
                              void* d_out, int out_size, void* d_ws, size_t ws_size,
                              hipStream_t stream) {
  const float* x   = (const float*)d_in[0];
  const float* W_w = (const float*)d_in[1];
  const float* W_b = (const float*)d_in[2];
  const float* a_w = (const float*)d_in[3];
  const float* a_b = (const float*)d_in[4];
  const int*   row = (const int*)d_in[5];
  const int*   col = (const int*)d_in[6];
  float* out = (float*)d_out;

  float* ws = (float*)d_ws;
  size_t off = 0;
  _Float16* Wh = (_Float16*)(ws + off); off += (size_t)NP * F / 2;       // fp16
  unsigned short* Wt = (unsigned short*)(ws + off); off += (F * F) / 2;  // bf16
  float* wa = ws + off;            off += 2 * F;
  float* cb = ws + off;            off += 8;
  float* f_dst = ws + off;         off += NP;
  float* f_row = ws + off;         off += NP;
  int* gcur = (int*)(ws + off);    off += NB;
  int2* rsc = (int2*)(ws + off);   off += 2 * (size_t)NP;
  float* inv_denom = (float*)(ws + off); off += NP;
  unsigned* gstage = (unsigned*)(ws + off); off += (size_t)NB * CAP;
  unsigned* csr = (unsigned*)(ws + off); off += (size_t)NB * CAP;
  int* bstart = (int*)(ws + off);  off += (size_t)NP * 8;
  (void)ws_size; (void)in_sizes; (void)n_in; (void)out_size;

  hipLaunchKernelGGL(prep_w, dim3(65), dim3(256), 0, stream, W_w, a_w, W_b,
                     a_b, Wt, wa, cb, gcur);
  hipLaunchKernelGGL(gemm_fvec_binA2, dim3(GEMM_BLOCKS + NAB + FVEC_SLOTS),
                     dim3(256), 0, stream, x, Wt, W_b, wa, row, col, Wh,
                     f_dst, f_row, gcur, gstage);
  hipLaunchKernelGGL(binB, dim3(NB), dim3(512), 0, stream, gcur, gstage,
                     f_dst, f_row, cb, rsc, inv_denom, csr, bstart);
  hipLaunchKernelGGL(gat_pull, dim3(PULL_BLOCKS), dim3(256), 0, stream,
                     rsc, csr, inv_denom, bstart, Wh, out);
}

// Round 4
// 284.150 us; speedup vs baseline: 1.7323x; 1.1699x over previous
//
#include <hip/hip_runtime.h>
#include <math.h>

#define N_NODES 50000
#define N_EDGES 1600000
#define F 256
#define ALPHA 0.2f
#define NP 50048   // padded node count (multiple of 128)
#define NB 196     // coarse buckets: bucket = row >> 8 (256 rows each)
#define CAP 10240  // fixed bucket capacity (Poisson mean 8192, sigma 91 -> 22σ)
#define EPB 4096   // edges per binning block
#define NAB ((N_EDGES + EPB - 1) / EPB)  // 391
#define GEMM_BLOCKS 782  // (NP/128) * (F/128)
#define FVEC_SLOTS 2048  // grid-stride fat blocks for the projection part
#define PULL_BLOCKS 2048 // persistent pull blocks (8 per CU)
#define NW_TOT (PULL_BLOCKS * 4)  // 8192 persistent waves
#define NPW 7    // nodes per wave (ceil(50000/8192))
#define NBIN 8   // col bins (col >> 13), 3.2 MB Wh slice per bin

typedef short bf16x8 __attribute__((ext_vector_type(8)));
typedef float f32x4 __attribute__((ext_vector_type(4)));
typedef _Float16 half4 __attribute__((ext_vector_type(4)));
typedef _Float16 half8 __attribute__((ext_vector_type(8)));

__device__ __forceinline__ unsigned short f2bf(float f) {
  union { float f; unsigned u; } v; v.f = f;
  unsigned u = v.u;
  return (unsigned short)((u + 0x7fffu + ((u >> 16) & 1u)) >> 16);
}

__device__ __forceinline__ unsigned short f2h_bits(float f) {
  union { _Float16 h; unsigned short u; } v;
  v.h = (_Float16)f;
  return v.u;
}

__device__ __forceinline__ float h_bits2f(unsigned short u) {
  union { _Float16 h; unsigned short u; } v;
  v.u = u;
  return (float)v.h;
}

// ---- L1: prep_w: W -> Wt bf16 transposed; wa = W @ a_halves; cb; zero gcur
__global__ __launch_bounds__(256) void prep_w(const float* __restrict__ W,
                                              const float* __restrict__ a_w,
                                              const float* __restrict__ W_b,
                                              const float* __restrict__ a_b,
                                              unsigned short* __restrict__ Wt,
                                              float* __restrict__ wa,
                                              float* __restrict__ cb,
                                              int* __restrict__ gcur) {
  if (blockIdx.x == 64) {  // zero the bucket cursors (replaces memset launch)
    if (threadIdx.x < NB) gcur[threadIdx.x] = 0;
    return;
  }
  const int lane = threadIdx.x & 63, w = threadIdx.x >> 6;
  const int k = blockIdx.x * 4 + w;  // 0..255
  float4 wv = *(const float4*)(W + (size_t)k * F + lane * 4);
  float4 a1 = *(const float4*)(a_w + lane * 4);
  float4 a2 = *(const float4*)(a_w + F + lane * 4);
  Wt[(size_t)(lane * 4 + 0) * F + k] = f2bf(wv.x);
  Wt[(size_t)(lane * 4 + 1) * F + k] = f2bf(wv.y);
  Wt[(size_t)(lane * 4 + 2) * F + k] = f2bf(wv.z);
  Wt[(size_t)(lane * 4 + 3) * F + k] = f2bf(wv.w);
  float s1 = wv.x * a1.x + wv.y * a1.y + wv.z * a1.z + wv.w * a1.w;
  float s2 = wv.x * a2.x + wv.y * a2.y + wv.z * a2.z + wv.w * a2.w;
#pragma unroll
  for (int off = 32; off > 0; off >>= 1) {
    s1 += __shfl_down(s1, off, 64);
    s2 += __shfl_down(s2, off, 64);
  }
  if (lane == 0) { wa[k] = s1; wa[F + k] = s2; }
  if (blockIdx.x == 0 && w == 0) {
    float4 b = *(const float4*)(W_b + lane * 4);
    float t1 = b.x * (a1.x + a2.x) + b.y * (a1.y + a2.y) +
               b.z * (a1.z + a2.z) + b.w * (a1.w + a2.w);
#pragma unroll
    for (int off = 32; off > 0; off >>= 1) t1 += __shfl_down(t1, off, 64);
    if (lane == 0) cb[0] = t1 + a_b[0];
  }
}

// ---- L2: fused GEMM [0,782) + binA2 [782,1173) + fvec [1173,1173+2048)
#define LDSK 72
__global__ __launch_bounds__(256) void gemm_fvec_binA2(
    const float* __restrict__ x,
    const unsigned short* __restrict__ Wt,
    const float* __restrict__ bias,
    const float* __restrict__ wa,
    const int* __restrict__ row,
    const int* __restrict__ col,
    _Float16* __restrict__ Wh,
    float* __restrict__ f_dst,
    float* __restrict__ f_row,
    int* __restrict__ gcur,
    unsigned* __restrict__ gstage) {
  __shared__ char smem[2 * 128 * LDSK * 2];  // 36864 B arena
  if (blockIdx.x < GEMM_BLOCKS) {
    // ---- GEMM part: Wh(fp16) = bf16(x) @ Wt^T + bias
    short* As = (short*)smem;
    short* Bs = As + 128 * LDSK;
    const int tid = threadIdx.x;
    const int lane = tid & 63;
    const int w = tid >> 6;
    const int wm = w >> 1, wn = w & 1;
    const int m0 = (blockIdx.x >> 1) * 128;
    const int n0 = (blockIdx.x & 1) * 128;
    f32x4 acc[4][4] = {{{0.f, 0.f, 0.f, 0.f}}};
    const int srow = tid >> 3;   // 0..31
    const int schunk = tid & 7;  // 0..7
    for (int k0 = 0; k0 < F; k0 += 64) {
#pragma unroll
      for (int i = 0; i < 4; ++i) {
        int r = i * 32 + srow;
        int gm = m0 + r; if (gm > N_NODES - 1) gm = N_NODES - 1;
        const float* src = x + (size_t)gm * F + k0 + schunk * 8;
        float4 lo = *(const float4*)src;
        float4 hi = *(const float4*)(src + 4);
        bf16x8 v;
        v[0] = (short)f2bf(lo.x); v[1] = (short)f2bf(lo.y);
        v[2] = (short)f2bf(lo.z); v[3] = (short)f2bf(lo.w);
        v[4] = (short)f2bf(hi.x); v[5] = (short)f2bf(hi.y);
        v[6] = (short)f2bf(hi.z); v[7] = (short)f2bf(hi.w);
        *(bf16x8*)&As[r * LDSK + schunk * 8] = v;
        *(bf16x8*)&Bs[r * LDSK + schunk * 8] =
            *(const bf16x8*)(Wt + (size_t)(n0 + r) * F + k0 + schunk * 8);
      }
      __syncthreads();
#pragma unroll
      for (int kk = 0; kk < 64; kk += 32) {
        const int rowsel = lane & 15;
        const int ksel = kk + (lane >> 4) * 8;
        bf16x8 af[4], bfr[4];
#pragma unroll
        for (int t = 0; t < 4; ++t) {
          af[t] = *(bf16x8*)&As[(wm * 64 + t * 16 + rowsel) * LDSK + ksel];
          bfr[t] = *(bf16x8*)&Bs[(wn * 64 + t * 16 + rowsel) * LDSK + ksel];
        }
#pragma unroll
        for (int mi = 0; mi < 4; ++mi)
#pragma unroll
          for (int nj = 0; nj < 4; ++nj)
            acc[mi][nj] = __builtin_amdgcn_mfma_f32_16x16x32_bf16(
                af[mi], bfr[nj], acc[mi][nj], 0, 0, 0);
      }
      __syncthreads();
    }
    const int crow = (lane >> 4) * 4;
    const int ccol = lane & 15;
#pragma unroll
    for (int nj = 0; nj < 4; ++nj) {
      int gc = n0 + wn * 64 + nj * 16 + ccol;
      float bv = bias[gc];
#pragma unroll
      for (int mi = 0; mi < 4; ++mi) {
        int gr = m0 + wm * 64 + mi * 16 + crow;
#pragma unroll
        for (int r = 0; r < 4; ++r)
          Wh[(size_t)(gr + r) * F + gc] = (_Float16)(acc[mi][nj][r] + bv);
      }
    }
    return;
  }
  if (blockIdx.x < GEMM_BLOCKS + NAB) {
    // ---- binA2 part
    int* h = (int*)smem;
    int* lofs = h + NB;
    int* lcur = lofs + NB;
    int* gb = lcur + NB;
    unsigned* stage = (unsigned*)(gb + NB);  // EPB entries
    const int t = threadIdx.x;
    for (int i = t; i < NB; i += 256) { h[i] = 0; lcur[i] = 0; }
    __syncthreads();
    const int base = (blockIdx.x - GEMM_BLOCKS) * EPB;
    const int cnt = min(EPB, N_EDGES - base);
#pragma unroll
    for (int j = 0; j < 16; ++j) {
      int k = base + j * 256 + t;
      if (k < N_EDGES) atomicAdd(&h[row[k] >> 8], 1);
    }
    __syncthreads();
    if (t == 0) {
      int run = 0;
      for (int i = 0; i < NB; ++i) { lofs[i] = run; run += h[i]; }
    }
    __syncthreads();
    if (t < NB && h[t] > 0) gb[t] = atomicAdd(&gcur[t], h[t]);
    __syncthreads();
#pragma unroll
    for (int j = 0; j < 16; ++j) {
      int k = base + j * 256 + t;
      if (k < N_EDGES) {
        int r = row[k], b = r >> 8;
        int lp = lofs[b] + atomicAdd(&lcur[b], 1);
        stage[lp] = ((unsigned)b << 24) | ((unsigned)(r & 255) << 16) |
                    (unsigned)col[k];
      }
    }
    __syncthreads();
#pragma unroll
    for (int j = 0; j < 16; ++j) {
      int s = j * 256 + t;
      if (s < cnt) {
        unsigned wv = stage[s];
        int b = wv >> 24;
        gstage[(size_t)b * CAP + gb[b] + (s - lofs[b])] = wv & 0x00FFFFFFu;
      }
    }
    return;
  }
  // ---- fvec part: grid-stride fat blocks (4 nodes/iter/block)
  const int lane = threadIdx.x & 63, w = threadIdx.x >> 6;
  const int slot = blockIdx.x - GEMM_BLOCKS - NAB;
  float4 v1 = *(const float4*)(wa + lane * 4);
  float4 v2 = *(const float4*)(wa + F + lane * 4);
  for (int node = slot * 4 + w; node < N_NODES; node += FVEC_SLOTS * 4) {
    float4 xv = *(const float4*)(x + (size_t)node * F + lane * 4);
    float s1 = xv.x * v1.x + xv.y * v1.y + xv.z * v1.z + xv.w * v1.w;
    float s2 = xv.x * v2.x + xv.y * v2.y + xv.z * v2.z + xv.w * v2.w;
#pragma unroll
    for (int off = 32; off > 0; off >>= 1) {
      s1 += __shfl_down(s1, off, 64);
      s2 += __shfl_down(s2, off, 64);
    }
    if (lane == 0) { f_dst[node] = s1; f_row[node] = s2; }
  }
}

// ---- L3: binB (512 thr): per-(row,colbin) histogram -> entries placed
// COL-SORTED within each row (8 bins, q = col>>13). Additionally exports the
// per-(row,bin) absolute start offsets (bstart) so the pull kernel can do a
// globally phase-synchronized bin sweep.
__global__ __launch_bounds__(512) void binB(const int* __restrict__ gcur,
                                            const unsigned* __restrict__ gstage,
                                            const float* __restrict__ f_dst,
                                            const float* __restrict__ f_row,
                                            const float* __restrict__ cb,
                                            int2* __restrict__ rsc,
                                            float* __restrict__ inv_denom,
                                            unsigned* __restrict__ csr,
                                            int* __restrict__ bstart) {
  __shared__ int cnt2[2048];  // per (row, colbin)
  __shared__ int cur2[2048];
  __shared__ int rcnt[256], rbase[256];
  __shared__ float dsum[256];
  const int t = threadIdx.x;
  const int b = blockIdx.x;
  for (int i = t; i < 2048; i += 512) cnt2[i] = 0;
  if (t < 256) dsum[t] = 0.f;
  __syncthreads();
  const int nb = gcur[b];
  const int start = b * CAP;
  const float cbs = cb[0];
  for (int s = t; s < nb; s += 512) {
    unsigned wv = gstage[start + s];
    int key = (((wv >> 16) & 255) << 3) | ((wv & 0xFFFFu) >> 13);
    atomicAdd(&cnt2[key], 1);
  }
  __syncthreads();
  if (t < 256) {
    int tot = 0;
#pragma unroll
    for (int q = 0; q < 8; ++q) tot += cnt2[t * 8 + q];
    rcnt[t] = tot;
  }
  __syncthreads();
  if (t == 0) {
    int run = 0;
    for (int i = 0; i < 256; ++i) { rbase[i] = run; run += rcnt[i]; }
  }
  __syncthreads();
  if (t < 256) {
    int base = start + rbase[t];
    int g = (b << 8) + t;
    if (g < N_NODES) rsc[g] = make_int2(base, rcnt[t]);
    int run = base;
    int bs[8];
#pragma unroll
    for (int q = 0; q < 8; ++q) {
      cur2[t * 8 + q] = run;
      bs[q] = run;
      run += cnt2[t * 8 + q];
    }
    if (g < N_NODES) {
      *(int4*)&bstart[(size_t)g * 8]     = make_int4(bs[0], bs[1], bs[2], bs[3]);
      *(int4*)&bstart[(size_t)g * 8 + 4] = make_int4(bs[4], bs[5], bs[6], bs[7]);
    }
  }
  __syncthreads();
  for (int s = t; s < nb; s += 512) {
    unsigned wv = gstage[start + s];
    int lr = (wv >> 16) & 255;
    int c = wv & 0xFFFF;
    float ev = f_dst[c] + f_row[(b << 8) + lr] + cbs;
    ev = ev > 0.f ? ev : ALPHA * ev;
    float ex = __expf(ev);
    int p = atomicAdd(&cur2[(lr << 3) | (c >> 13)], 1);  // absolute index
    csr[p] = ((unsigned)f2h_bits(ex) << 16) | (unsigned)c;
    atomicAdd(&dsum[lr], ex);
  }
  __syncthreads();
  if (t < 256) {
    int g = (b << 8) + t;
    if (g < N_NODES) inv_denom[g] = (rcnt[t] > 0) ? (1.0f / dsum[t]) : 0.f;
  }
}

// ---- L4: pull, phase-synchronized col-bin sweep, MLP edition.
// Traffic structure of round-3 (FETCH 227 MB, proven) with the latency
// structure fixed:
//  * segment bounds staged in LDS once per block (no global loads in the
//    per-segment critical path),
//  * ONE csr cache-line load per segment (lane & 15), edges extracted with
//    v_readlane -> all gathers within a segment are independent,
//  * next node's csr line prefetched while current node is processed.
// Persistent state: 4 f32 acc x NPW=7 nodes = 28 VGPR (spill-proof).
__global__ __launch_bounds__(256) void gat_pull(const int2* __restrict__ rsc,
                                                const unsigned* __restrict__ csr,
                                                const float* __restrict__ inv_denom,
                                                const int* __restrict__ bstart,
                                                const _Float16* __restrict__ Wh,
                                                float* __restrict__ out) {
  __shared__ int sb[4 * NPW * 9];  // 4 waves x 7 nodes x (8 starts + row end)
  const int lane = threadIdx.x & 63;
  const int wv_id = threadIdx.x >> 6;
  const int wid = blockIdx.x * 4 + wv_id;
  // cooperative bounds stage: entry e = w*63 + jn*9 + q
  for (int e = threadIdx.x; e < 4 * NPW * 9; e += 256) {
    int w = e / (NPW * 9);
    int rem = e - w * (NPW * 9);
    int jn = rem / 9, q = rem - jn * 9;
    int i = blockIdx.x * 4 + w + jn * NW_TOT;
    int v = 0;
    if (i < N_NODES) {
      if (q < 8) v = bstart[(size_t)i * 8 + q];
      else { int2 rc = rsc[i]; v = rc.x + rc.y; }
    }
    sb[e] = v;
  }
  __syncthreads();
  const int* mb = &sb[wv_id * NPW * 9];
  const char* whb = (const char*)Wh;
  const unsigned chanoff = (unsigned)lane * 8u;  // 4 fp16 channels / lane
  const int l16 = lane & 15;
  float a0[NPW], a1[NPW], a2[NPW], a3[NPW];
#pragma unroll
  for (int jn = 0; jn < NPW; ++jn) a0[jn] = a1[jn] = a2[jn] = a3[jn] = 0.f;
  for (int q = 0; q < NBIN; ++q) {
    // prefetch jn=0 segment csr line
    int pp = mb[q], pe = mb[q + 1];
    unsigned cw0 = 0;
    if (pp + l16 < pe) cw0 = csr[pp + l16];
#pragma unroll
    for (int jn = 0; jn < NPW; ++jn) {
      const int cpp = pp, cpe = pe;
      unsigned cw = cw0;
      if (jn + 1 < NPW) {  // prefetch next node's segment
        pp = mb[(jn + 1) * 9 + q];
        pe = mb[(jn + 1) * 9 + q + 1];
        cw0 = 0;
        if (pp + l16 < pe) cw0 = csr[pp + l16];
      }
      int len = cpe - cpp;
      int done = 0;
      while (done < len) {
        int cl = len - done;
        if (cl > 16) cl = 16;
        if (done) {  // chunks beyond the first: reload line
          cw = 0;
          if (cpp + done + l16 < cpe) cw = csr[cpp + done + l16];
        }
        for (int j = 0; j < cl; ++j) {
          unsigned wj = __builtin_amdgcn_readlane(cw, (unsigned)j);
          half4 v = *(const half4*)(whb + (size_t)(wj & 0xFFFFu) * 512u +
                                    chanoff);
          float xw = h_bits2f((unsigned short)(wj >> 16));
          a0[jn] += xw * (float)v[0];
          a1[jn] += xw * (float)v[1];
          a2[jn] += xw * (float)v[2];
          a3[jn] += xw * (float)v[3];
        }
        done += 16;
      }
    }
  }
  // finalize: scale, relu, store (lane owns its 4 channels directly)
#pragma unroll
  for (int jn = 0; jn < NPW; ++jn) {
    int i = wid + jn * NW_TOT;
    if (i >= N_NODES) continue;
    const float inv = inv_denom[i];
    float4 o = make_float4(fmaxf(a0[jn] * inv, 0.f), fmaxf(a1[jn] * inv, 0.f),
                           fmaxf(a2[jn] * inv, 0.f), fmaxf(a3[jn] * inv, 0.f));
    ((float4*)out)[(size_t)i * 64 + lane] = o;
  }
}

extern "C" void kernel_launch(void* const* d_in, const int* in_sizes, int n_in,
                              void* d_out, int out_size, void* d_ws, size_t ws_size,
                              hipStream_t stream) {
  const float* x   = (const float*)d_in[0];
  const float* W_w = (const float*)d_in[1];
  const float* W_b = (const float*)d_in[2];
  const float* a_w = (const float*)d_in[3];
  const float* a_b = (const float*)d_in[4];
  const int*   row = (const int*)d_in[5];
  const int*   col = (const int*)d_in[6];
  float* out = (float*)d_out;

  float* ws = (float*)d_ws;
  size_t off = 0;
  _Float16* Wh = (_Float16*)(ws + off); off += (size_t)NP * F / 2;       // fp16
  unsigned short* Wt = (unsigned short*)(ws + off); off += (F * F) / 2;  // bf16
  float* wa = ws + off;            off += 2 * F;
  float* cb = ws + off;            off += 8;
  float* f_dst = ws + off;         off += NP;
  float* f_row = ws + off;         off += NP;
  int* gcur = (int*)(ws + off);    off += NB;
  int2* rsc = (int2*)(ws + off);   off += 2 * (size_t)NP;
  float* inv_denom = (float*)(ws + off); off += NP;
  unsigned* gstage = (unsigned*)(ws + off); off += (size_t)NB * CAP;
  unsigned* csr = (unsigned*)(ws + off); off += (size_t)NB * CAP;
  int* bstart = (int*)(ws + off);  off += (size_t)NP * 8;
  (void)ws_size; (void)in_sizes; (void)n_in; (void)out_size;

  hipLaunchKernelGGL(prep_w, dim3(65), dim3(256), 0, stream, W_w, a_w, W_b,
                     a_b, Wt, wa, cb, gcur);
  hipLaunchKernelGGL(gemm_fvec_binA2, dim3(GEMM_BLOCKS + NAB + FVEC_SLOTS),
                     dim3(256), 0, stream, x, Wt, W_b, wa, row, col, Wh,
                     f_dst, f_row, gcur, gstage);
  hipLaunchKernelGGL(binB, dim3(NB), dim3(512), 0, stream, gcur, gstage,
                     f_dst, f_row, cb, rsc, inv_denom, csr, bstart);
  hipLaunchKernelGGL(gat_pull, dim3(PULL_BLOCKS), dim3(256), 0, stream,
                     rsc, csr, inv_denom, bstart, Wh, out);
}

// Round 5
// 264.881 us; speedup vs baseline: 1.8584x; 1.0727x over previous
//
#include <hip/hip_runtime.h>
#include <math.h>

#define N_NODES 50000
#define N_EDGES 1600000
#define F 256
#define ALPHA 0.2f
#define NP 50048   // padded node count (multiple of 128)
#define NB 196     // coarse buckets: bucket = row >> 8 (256 rows each)
#define CAP 10240  // fixed bucket capacity (Poisson mean 8192, sigma 91 -> 22σ)
#define EPB 4096   // edges per binning block
#define NAB ((N_EDGES + EPB - 1) / EPB)  // 391
#define GEMM_BLOCKS 782  // (NP/128) * (F/128)
#define FVEC_SLOTS 2048  // grid-stride fat blocks for the projection part
#define PULL_BLOCKS 2048 // persistent pull blocks (8 per CU)
#define NW_TOT (PULL_BLOCKS * 4)  // 8192 persistent waves
#define NPW 7    // nodes per wave (ceil(50000/8192))
#define NBIN 8   // col bins (col >> 13), 3.2 MB Wh slice per bin

typedef short bf16x8 __attribute__((ext_vector_type(8)));
typedef float f32x4 __attribute__((ext_vector_type(4)));
typedef _Float16 half4 __attribute__((ext_vector_type(4)));
typedef _Float16 half8 __attribute__((ext_vector_type(8)));

__device__ __forceinline__ unsigned short f2bf(float f) {
  union { float f; unsigned u; } v; v.f = f;
  unsigned u = v.u;
  return (unsigned short)((u + 0x7fffu + ((u >> 16) & 1u)) >> 16);
}

__device__ __forceinline__ unsigned short f2h_bits(float f) {
  union { _Float16 h; unsigned short u; } v;
  v.h = (_Float16)f;
  return v.u;
}

__device__ __forceinline__ float h_bits2f(unsigned short u) {
  union { _Float16 h; unsigned short u; } v;
  v.u = u;
  return (float)v.h;
}

// ---- L1: prep_w: W -> Wt bf16 transposed; wa = W @ a_halves; cb; zero gcur
__global__ __launch_bounds__(256) void prep_w(const float* __restrict__ W,
                                              const float* __restrict__ a_w,
                                              const float* __restrict__ W_b,
                                              const float* __restrict__ a_b,
                                              unsigned short* __restrict__ Wt,
                                              float* __restrict__ wa,
                                              float* __restrict__ cb,
                                              int* __restrict__ gcur) {
  if (blockIdx.x == 64) {  // zero the bucket cursors (replaces memset launch)
    if (threadIdx.x < NB) gcur[threadIdx.x] = 0;
    return;
  }
  const int lane = threadIdx.x & 63, w = threadIdx.x >> 6;
  const int k = blockIdx.x * 4 + w;  // 0..255
  float4 wv = *(const float4*)(W + (size_t)k * F + lane * 4);
  float4 a1 = *(const float4*)(a_w + lane * 4);
  float4 a2 = *(const float4*)(a_w + F + lane * 4);
  Wt[(size_t)(lane * 4 + 0) * F + k] = f2bf(wv.x);
  Wt[(size_t)(lane * 4 + 1) * F + k] = f2bf(wv.y);
  Wt[(size_t)(lane * 4 + 2) * F + k] = f2bf(wv.z);
  Wt[(size_t)(lane * 4 + 3) * F + k] = f2bf(wv.w);
  float s1 = wv.x * a1.x + wv.y * a1.y + wv.z * a1.z + wv.w * a1.w;
  float s2 = wv.x * a2.x + wv.y * a2.y + wv.z * a2.z + wv.w * a2.w;
#pragma unroll
  for (int off = 32; off > 0; off >>= 1) {
    s1 += __shfl_down(s1, off, 64);
    s2 += __shfl_down(s2, off, 64);
  }
  if (lane == 0) { wa[k] = s1; wa[F + k] = s2; }
  if (blockIdx.x == 0 && w == 0) {
    float4 b = *(const float4*)(W_b + lane * 4);
    float t1 = b.x * (a1.x + a2.x) + b.y * (a1.y + a2.y) +
               b.z * (a1.z + a2.z) + b.w * (a1.w + a2.w);
#pragma unroll
    for (int off = 32; off > 0; off >>= 1) t1 += __shfl_down(t1, off, 64);
    if (lane == 0) cb[0] = t1 + a_b[0];
  }
}

// ---- L2: fused GEMM [0,782) + binA2 [782,1173) + fvec [1173,1173+2048)
#define LDSK 72
__global__ __launch_bounds__(256) void gemm_fvec_binA2(
    const float* __restrict__ x,
    const unsigned short* __restrict__ Wt,
    const float* __restrict__ bias,
    const float* __restrict__ wa,
    const int* __restrict__ row,
    const int* __restrict__ col,
    _Float16* __restrict__ Wh,
    float* __restrict__ f_dst,
    float* __restrict__ f_row,
    int* __restrict__ gcur,
    unsigned* __restrict__ gstage) {
  __shared__ char smem[2 * 128 * LDSK * 2];  // 36864 B arena
  if (blockIdx.x < GEMM_BLOCKS) {
    // ---- GEMM part: Wh(fp16) = bf16(x) @ Wt^T + bias
    short* As = (short*)smem;
    short* Bs = As + 128 * LDSK;
    const int tid = threadIdx.x;
    const int lane = tid & 63;
    const int w = tid >> 6;
    const int wm = w >> 1, wn = w & 1;
    const int m0 = (blockIdx.x >> 1) * 128;
    const int n0 = (blockIdx.x & 1) * 128;
    f32x4 acc[4][4] = {{{0.f, 0.f, 0.f, 0.f}}};
    const int srow = tid >> 3;   // 0..31
    const int schunk = tid & 7;  // 0..7
    for (int k0 = 0; k0 < F; k0 += 64) {
#pragma unroll
      for (int i = 0; i < 4; ++i) {
        int r = i * 32 + srow;
        int gm = m0 + r; if (gm > N_NODES - 1) gm = N_NODES - 1;
        const float* src = x + (size_t)gm * F + k0 + schunk * 8;
        float4 lo = *(const float4*)src;
        float4 hi = *(const float4*)(src + 4);
        bf16x8 v;
        v[0] = (short)f2bf(lo.x); v[1] = (short)f2bf(lo.y);
        v[2] = (short)f2bf(lo.z); v[3] = (short)f2bf(lo.w);
        v[4] = (short)f2bf(hi.x); v[5] = (short)f2bf(hi.y);
        v[6] = (short)f2bf(hi.z); v[7] = (short)f2bf(hi.w);
        *(bf16x8*)&As[r * LDSK + schunk * 8] = v;
        *(bf16x8*)&Bs[r * LDSK + schunk * 8] =
            *(const bf16x8*)(Wt + (size_t)(n0 + r) * F + k0 + schunk * 8);
      }
      __syncthreads();
#pragma unroll
      for (int kk = 0; kk < 64; kk += 32) {
        const int rowsel = lane & 15;
        const int ksel = kk + (lane >> 4) * 8;
        bf16x8 af[4], bfr[4];
#pragma unroll
        for (int t = 0; t < 4; ++t) {
          af[t] = *(bf16x8*)&As[(wm * 64 + t * 16 + rowsel) * LDSK + ksel];
          bfr[t] = *(bf16x8*)&Bs[(wn * 64 + t * 16 + rowsel) * LDSK + ksel];
        }
#pragma unroll
        for (int mi = 0; mi < 4; ++mi)
#pragma unroll
          for (int nj = 0; nj < 4; ++nj)
            acc[mi][nj] = __builtin_amdgcn_mfma_f32_16x16x32_bf16(
                af[mi], bfr[nj], acc[mi][nj], 0, 0, 0);
      }
      __syncthreads();
    }
    const int crow = (lane >> 4) * 4;
    const int ccol = lane & 15;
#pragma unroll
    for (int nj = 0; nj < 4; ++nj) {
      int gc = n0 + wn * 64 + nj * 16 + ccol;
      float bv = bias[gc];
#pragma unroll
      for (int mi = 0; mi < 4; ++mi) {
        int gr = m0 + wm * 64 + mi * 16 + crow;
#pragma unroll
        for (int r = 0; r < 4; ++r)
          Wh[(size_t)(gr + r) * F + gc] = (_Float16)(acc[mi][nj][r] + bv);
      }
    }
    return;
  }
  if (blockIdx.x < GEMM_BLOCKS + NAB) {
    // ---- binA2 part
    int* h = (int*)smem;
    int* lofs = h + NB;
    int* lcur = lofs + NB;
    int* gb = lcur + NB;
    unsigned* stage = (unsigned*)(gb + NB);  // EPB entries
    const int t = threadIdx.x;
    for (int i = t; i < NB; i += 256) { h[i] = 0; lcur[i] = 0; }
    __syncthreads();
    const int base = (blockIdx.x - GEMM_BLOCKS) * EPB;
    const int cnt = min(EPB, N_EDGES - base);
#pragma unroll
    for (int j = 0; j < 16; ++j) {
      int k = base + j * 256 + t;
      if (k < N_EDGES) atomicAdd(&h[row[k] >> 8], 1);
    }
    __syncthreads();
    if (t == 0) {
      int run = 0;
      for (int i = 0; i < NB; ++i) { lofs[i] = run; run += h[i]; }
    }
    __syncthreads();
    if (t < NB && h[t] > 0) gb[t] = atomicAdd(&gcur[t], h[t]);
    __syncthreads();
#pragma unroll
    for (int j = 0; j < 16; ++j) {
      int k = base + j * 256 + t;
      if (k < N_EDGES) {
        int r = row[k], b = r >> 8;
        int lp = lofs[b] + atomicAdd(&lcur[b], 1);
        stage[lp] = ((unsigned)b << 24) | ((unsigned)(r & 255) << 16) |
                    (unsigned)col[k];
      }
    }
    __syncthreads();
#pragma unroll
    for (int j = 0; j < 16; ++j) {
      int s = j * 256 + t;
      if (s < cnt) {
        unsigned wv = stage[s];
        int b = wv >> 24;
        gstage[(size_t)b * CAP + gb[b] + (s - lofs[b])] = wv & 0x00FFFFFFu;
      }
    }
    return;
  }
  // ---- fvec part: grid-stride fat blocks (4 nodes/iter/block)
  const int lane = threadIdx.x & 63, w = threadIdx.x >> 6;
  const int slot = blockIdx.x - GEMM_BLOCKS - NAB;
  float4 v1 = *(const float4*)(wa + lane * 4);
  float4 v2 = *(const float4*)(wa + F + lane * 4);
  for (int node = slot * 4 + w; node < N_NODES; node += FVEC_SLOTS * 4) {
    float4 xv = *(const float4*)(x + (size_t)node * F + lane * 4);
    float s1 = xv.x * v1.x + xv.y * v1.y + xv.z * v1.z + xv.w * v1.w;
    float s2 = xv.x * v2.x + xv.y * v2.y + xv.z * v2.z + xv.w * v2.w;
#pragma unroll
    for (int off = 32; off > 0; off >>= 1) {
      s1 += __shfl_down(s1, off, 64);
      s2 += __shfl_down(s2, off, 64);
    }
    if (lane == 0) { f_dst[node] = s1; f_row[node] = s2; }
  }
}

// ---- L3: binB (512 thr): per-(row,colbin) histogram -> entries placed
// COL-SORTED within each row (8 bins, q = col>>13). Additionally exports the
// per-(row,bin) absolute start offsets (bstart) so the pull kernel can do a
// globally phase-synchronized bin sweep.
__global__ __launch_bounds__(512) void binB(const int* __restrict__ gcur,
                                            const unsigned* __restrict__ gstage,
                                            const float* __restrict__ f_dst,
                                            const float* __restrict__ f_row,
                                            const float* __restrict__ cb,
                                            int2* __restrict__ rsc,
                                            float* __restrict__ inv_denom,
                                            unsigned* __restrict__ csr,
                                            int* __restrict__ bstart) {
  __shared__ int cnt2[2048];  // per (row, colbin)
  __shared__ int cur2[2048];
  __shared__ int rcnt[256], rbase[256];
  __shared__ float dsum[256];
  const int t = threadIdx.x;
  const int b = blockIdx.x;
  for (int i = t; i < 2048; i += 512) cnt2[i] = 0;
  if (t < 256) dsum[t] = 0.f;
  __syncthreads();
  const int nb = gcur[b];
  const int start = b * CAP;
  const float cbs = cb[0];
  for (int s = t; s < nb; s += 512) {
    unsigned wv = gstage[start + s];
    int key = (((wv >> 16) & 255) << 3) | ((wv & 0xFFFFu) >> 13);
    atomicAdd(&cnt2[key], 1);
  }
  __syncthreads();
  if (t < 256) {
    int tot = 0;
#pragma unroll
    for (int q = 0; q < 8; ++q) tot += cnt2[t * 8 + q];
    rcnt[t] = tot;
  }
  __syncthreads();
  if (t == 0) {
    int run = 0;
    for (int i = 0; i < 256; ++i) { rbase[i] = run; run += rcnt[i]; }
  }
  __syncthreads();
  if (t < 256) {
    int base = start + rbase[t];
    int g = (b << 8) + t;
    if (g < N_NODES) rsc[g] = make_int2(base, rcnt[t]);
    int run = base;
    int bs[8];
#pragma unroll
    for (int q = 0; q < 8; ++q) {
      cur2[t * 8 + q] = run;
      bs[q] = run;
      run += cnt2[t * 8 + q];
    }
    if (g < N_NODES) {
      *(int4*)&bstart[(size_t)g * 8]     = make_int4(bs[0], bs[1], bs[2], bs[3]);
      *(int4*)&bstart[(size_t)g * 8 + 4] = make_int4(bs[4], bs[5], bs[6], bs[7]);
    }
  }
  __syncthreads();
  for (int s = t; s < nb; s += 512) {
    unsigned wv = gstage[start + s];
    int lr = (wv >> 16) & 255;
    int c = wv & 0xFFFF;
    float ev = f_dst[c] + f_row[(b << 8) + lr] + cbs;
    ev = ev > 0.f ? ev : ALPHA * ev;
    float ex = __expf(ev);
    int p = atomicAdd(&cur2[(lr << 3) | (c >> 13)], 1);  // absolute index
    csr[p] = ((unsigned)f2h_bits(ex) << 16) | (unsigned)c;
    atomicAdd(&dsum[lr], ex);
  }
  __syncthreads();
  if (t < 256) {
    int g = (b << 8) + t;
    if (g < N_NODES) inv_denom[g] = (rcnt[t] > 0) ? (1.0f / dsum[t]) : 0.f;
  }
}

// ---- L4: pull, phase-synchronized col-bin sweep, 4-deep MLP edition.
// Round-4 traffic structure (FETCH 190 MB, proven) with the gather-issue
// fixed: the per-edge loop is restructured into fixed 4-edge batches --
// 4 uniform readlane extracts (SALU), 4 INDEPENDENT half4 gathers issued
// back-to-back, then 16 FMAs with clamped weights. Pad edges (j >= cl)
// reuse edge 0's address: line already resident, weight zeroed.
// MLP per wave: 1 -> 4 outstanding gathers (+ next-node csr prefetch).
__global__ __launch_bounds__(256) void gat_pull(const int2* __restrict__ rsc,
                                                const unsigned* __restrict__ csr,
                                                const float* __restrict__ inv_denom,
                                                const int* __restrict__ bstart,
                                                const _Float16* __restrict__ Wh,
                                                float* __restrict__ out) {
  __shared__ int sb[4 * NPW * 9];  // 4 waves x 7 nodes x (8 starts + row end)
  const int lane = threadIdx.x & 63;
  const int wv_id = threadIdx.x >> 6;
  const int wid = blockIdx.x * 4 + wv_id;
  // cooperative bounds stage: entry e = w*63 + jn*9 + q
  for (int e = threadIdx.x; e < 4 * NPW * 9; e += 256) {
    int w = e / (NPW * 9);
    int rem = e - w * (NPW * 9);
    int jn = rem / 9, q = rem - jn * 9;
    int i = blockIdx.x * 4 + w + jn * NW_TOT;
    int v = 0;
    if (i < N_NODES) {
      if (q < 8) v = bstart[(size_t)i * 8 + q];
      else { int2 rc = rsc[i]; v = rc.x + rc.y; }
    }
    sb[e] = v;
  }
  __syncthreads();
  const int* mb = &sb[wv_id * NPW * 9];
  const char* whb = (const char*)Wh;
  const unsigned chanoff = (unsigned)lane * 8u;  // 4 fp16 channels / lane
  const int l16 = lane & 15;
  float a0[NPW], a1[NPW], a2[NPW], a3[NPW];
#pragma unroll
  for (int jn = 0; jn < NPW; ++jn) a0[jn] = a1[jn] = a2[jn] = a3[jn] = 0.f;
  for (int q = 0; q < NBIN; ++q) {
    // prefetch jn=0 segment csr line
    int pp = mb[q], pe = mb[q + 1];
    unsigned cw0 = 0;
    if (pp + l16 < pe) cw0 = csr[pp + l16];
#pragma unroll
    for (int jn = 0; jn < NPW; ++jn) {
      const int cpp = pp, cpe = pe;
      unsigned cw = cw0;
      if (jn + 1 < NPW) {  // prefetch next node's segment
        pp = mb[(jn + 1) * 9 + q];
        pe = mb[(jn + 1) * 9 + q + 1];
        cw0 = 0;
        if (pp + l16 < pe) cw0 = csr[pp + l16];
      }
      const int len = cpe - cpp;
      for (int done = 0; done < len; done += 16) {
        if (done) {  // chunks beyond the first: reload line (rare, len>16)
          cw = 0;
          if (cpp + done + l16 < cpe) cw = csr[cpp + done + l16];
        }
        int cl = len - done;
        if (cl > 16) cl = 16;
        for (int jb = 0; jb < cl; jb += 4) {
          // 4-edge batch: uniform extracts, clamped to edge 0 when past end
          const int j1 = (jb + 1 < cl) ? jb + 1 : 0;
          const int j2 = (jb + 2 < cl) ? jb + 2 : 0;
          const int j3 = (jb + 3 < cl) ? jb + 3 : 0;
          unsigned w0 = __builtin_amdgcn_readlane(cw, jb);
          unsigned w1 = __builtin_amdgcn_readlane(cw, j1);
          unsigned w2 = __builtin_amdgcn_readlane(cw, j2);
          unsigned w3 = __builtin_amdgcn_readlane(cw, j3);
          half4 v0 = *(const half4*)(whb + (size_t)(w0 & 0xFFFFu) * 512u + chanoff);
          half4 v1 = *(const half4*)(whb + (size_t)(w1 & 0xFFFFu) * 512u + chanoff);
          half4 v2 = *(const half4*)(whb + (size_t)(w2 & 0xFFFFu) * 512u + chanoff);
          half4 v3 = *(const half4*)(whb + (size_t)(w3 & 0xFFFFu) * 512u + chanoff);
          float x0 = h_bits2f((unsigned short)(w0 >> 16));
          float x1 = (jb + 1 < cl) ? h_bits2f((unsigned short)(w1 >> 16)) : 0.f;
          float x2 = (jb + 2 < cl) ? h_bits2f((unsigned short)(w2 >> 16)) : 0.f;
          float x3 = (jb + 3 < cl) ? h_bits2f((unsigned short)(w3 >> 16)) : 0.f;
          a0[jn] += x0 * (float)v0[0]; a1[jn] += x0 * (float)v0[1];
          a2[jn] += x0 * (float)v0[2]; a3[jn] += x0 * (float)v0[3];
          a0[jn] += x1 * (float)v1[0]; a1[jn] += x1 * (float)v1[1];
          a2[jn] += x1 * (float)v1[2]; a3[jn] += x1 * (float)v1[3];
          a0[jn] += x2 * (float)v2[0]; a1[jn] += x2 * (float)v2[1];
          a2[jn] += x2 * (float)v2[2]; a3[jn] += x2 * (float)v2[3];
          a0[jn] += x3 * (float)v3[0]; a1[jn] += x3 * (float)v3[1];
          a2[jn] += x3 * (float)v3[2]; a3[jn] += x3 * (float)v3[3];
        }
      }
    }
  }
  // finalize: scale, relu, store (lane owns its 4 channels directly)
#pragma unroll
  for (int jn = 0; jn < NPW; ++jn) {
    int i = wid + jn * NW_TOT;
    if (i >= N_NODES) continue;
    const float inv = inv_denom[i];
    float4 o = make_float4(fmaxf(a0[jn] * inv, 0.f), fmaxf(a1[jn] * inv, 0.f),
                           fmaxf(a2[jn] * inv, 0.f), fmaxf(a3[jn] * inv, 0.f));
    ((float4*)out)[(size_t)i * 64 + lane] = o;
  }
}

extern "C" void kernel_launch(void* const* d_in, const int* in_sizes, int n_in,
                              void* d_out, int out_size, void* d_ws, size_t ws_size,
                              hipStream_t stream) {
  const float* x   = (const float*)d_in[0];
  const float* W_w = (const float*)d_in[1];
  const float* W_b = (const float*)d_in[2];
  const float* a_w = (const float*)d_in[3];
  const float* a_b = (const float*)d_in[4];
  const int*   row = (const int*)d_in[5];
  const int*   col = (const int*)d_in[6];
  float* out = (float*)d_out;

  float* ws = (float*)d_ws;
  size_t off = 0;
  _Float16* Wh = (_Float16*)(ws + off); off += (size_t)NP * F / 2;       // fp16
  unsigned short* Wt = (unsigned short*)(ws + off); off += (F * F) / 2;  // bf16
  float* wa = ws + off;            off += 2 * F;
  float* cb = ws + off;            off += 8;
  float* f_dst = ws + off;         off += NP;
  float* f_row = ws + off;         off += NP;
  int* gcur = (int*)(ws + off);    off += NB;
  int2* rsc = (int2*)(ws + off);   off += 2 * (size_t)NP;
  float* inv_denom = (float*)(ws + off); off += NP;
  unsigned* gstage = (unsigned*)(ws + off); off += (size_t)NB * CAP;
  unsigned* csr = (unsigned*)(ws + off); off += (size_t)NB * CAP;
  int* bstart = (int*)(ws + off);  off += (size_t)NP * 8;
  (void)ws_size; (void)in_sizes; (void)n_in; (void)out_size;

  hipLaunchKernelGGL(prep_w, dim3(65), dim3(256), 0, stream, W_w, a_w, W_b,
                     a_b, Wt, wa, cb, gcur);
  hipLaunchKernelGGL(gemm_fvec_binA2, dim3(GEMM_BLOCKS + NAB + FVEC_SLOTS),
                     dim3(256), 0, stream, x, Wt, W_b, wa, row, col, Wh,
                     f_dst, f_row, gcur, gstage);
  hipLaunchKernelGGL(binB, dim3(NB), dim3(512), 0, stream, gcur, gstage,
                     f_dst, f_row, cb, rsc, inv_denom, csr, bstart);
  hipLaunchKernelGGL(gat_pull, dim3(PULL_BLOCKS), dim3(256), 0, stream,
                     rsc, csr, inv_denom, bstart, Wh, out);
}